// Round 15
// baseline (431.705 us; speedup 1.0000x reference)
//
#include <hip/hip_runtime.h>
#include <hip/hip_fp16.h>

#define N_NODES 50000
#define N_HID   64
#define N_LAYER 4
#define N_CLASS 40
#define N_EDGES 800000

#define BSHIFT 8
#define BSIZE  256                                      // nodes per bucket
#define NBUCK  ((N_NODES + BSIZE - 1) / BSIZE)          // 196
#define BPAD   16                                       // bucket-cursor stride (64B)
#define EPT    16                                       // edges per thread (bucket pass)
#define BKCHUNK (256 * EPT)                             // 4096 edges per block
#define NBBLK  ((N_EDGES + BKCHUNK - 1) / BKCHUNK)      // 196

#define SCAP  5120                                      // fixed stag window per bucket
#define PBK   (SCAP + 15 * BSIZE)                       // 8960: padded (x16) CSR window
#define DUMMY N_NODES                                   // index of zeroed hd row

#define NGRP4  (N_NODES / 4)                            // 12500 4-node agg groups
#define NGRP16 (N_NODES / 16)                           // 3125 16-node gemm0 groups
#define PGRID  2048                                     // persistent grid (8 blocks/CU)

// ---------------- init: bucket cursors + dummy hd rows ----------------

__global__ void k_zerob(int* __restrict__ bcur, __half* __restrict__ hdA,
                        __half* __restrict__ hdB) {
    int t = threadIdx.x;
    if (t < NBUCK) bcur[t * BPAD] = t * SCAP;
    if (t < 64) {
        hdA[(size_t)N_NODES * 64 + t] = __float2half(0.f);
        hdB[(size_t)N_NODES * 64 + t] = __float2half(0.f);
    }
}

// ---------------- block-binned append of packed (dst<<16)|src into fixed bucket windows ----------------

__global__ void k_bucket(const int* __restrict__ src, const int* __restrict__ dst,
                         int* __restrict__ bcur, unsigned int* __restrict__ stag) {
    __shared__ int lhist[NBUCK];
    __shared__ int gbase[NBUCK];
    int t = threadIdx.x;
    for (int i = t; i < NBUCK; i += 256) lhist[i] = 0;
    __syncthreads();

    int base = blockIdx.x * BKCHUNK;
    unsigned int rec[EPT];
    int br[EPT];
#pragma unroll
    for (int i = 0; i < EPT; i++) {
        int e = base + i * 256 + t;      // coalesced
        if (e < N_EDGES) {
            int d = dst[e], s = src[e];
            int b = d >> BSHIFT;
            int r = atomicAdd(&lhist[b], 1);   // in-block rank within bucket
            rec[i] = ((unsigned int)d << 16) | (unsigned int)s;
            br[i]  = (b << 16) | r;            // r < 4096
        } else {
            br[i] = -1;
        }
    }
    __syncthreads();
    for (int i = t; i < NBUCK; i += 256) {
        int c = lhist[i];
        gbase[i] = c ? atomicAdd(&bcur[i * BPAD], c) : 0;
    }
    __syncthreads();
#pragma unroll
    for (int i = 0; i < EPT; i++) {
        if (br[i] >= 0) {
            int b = br[i] >> 16, r = br[i] & 0xffff;
            stag[gbase[b] + r] = rec[i];
        }
    }
}

// ---------------- per-bucket: LDS count + scan -> CSR rows padded to x16 ----------------

__global__ void k_csr2(const unsigned int* __restrict__ stag, const int* __restrict__ bcur,
                       int* __restrict__ cnt, int* __restrict__ pcurg,
                       float* __restrict__ dinv, unsigned short* __restrict__ csr16) {
    __shared__ int lcnt[BSIZE], ltmp[BSIZE], lcur[BSIZE];
    int b = blockIdx.x, t = threadIdx.x;
    int bstart = b * SCAP;
    int bend   = bcur[b * BPAD];         // post-append cursor = bucket end
    lcnt[t] = 0;
    __syncthreads();
    for (int i = bstart + t; i < bend; i += 256)
        atomicAdd(&lcnt[(stag[i] >> 16) & (BSIZE - 1)], 1);
    __syncthreads();
    int v = lcnt[t];
    int p = (v + 15) & ~15;              // padded row size (x16)
    ltmp[t] = p;
    __syncthreads();
    for (int off = 1; off < 256; off <<= 1) {
        int u = (t >= off) ? ltmp[t - off] : 0;
        __syncthreads();
        ltmp[t] += u;
        __syncthreads();
    }
    int pstart = b * PBK + ltmp[t] - p;  // node's padded CSR row start (x16 aligned)
    lcur[t] = pstart;
    int node = (b << BSHIFT) + t;
    if (node < N_NODES) {
        cnt[node]   = v;
        pcurg[node] = pstart;
        dinv[node]  = rsqrtf((float)(v + 1));
    }
    __syncthreads();
    for (int i = bstart + t; i < bend; i += 256) {
        unsigned int rec = stag[i];
        int pos = atomicAdd(&lcur[(rec >> 16) & (BSIZE - 1)], 1);
        csr16[pos] = (unsigned short)rec;
    }
    for (int i = v; i < p; i++)          // fill pad slots with dummy zero-row
        csr16[pstart + i] = (unsigned short)DUMMY;
}

// ---------------- layer-0 GEMM (persistent, tiled 4 acc/thread) ----------------

__global__ __launch_bounds__(256) void k_gemm0(const float* __restrict__ A,
                                               const float* __restrict__ W,
                                               const float* __restrict__ dinv,
                                               __half* __restrict__ hd) {
    __shared__ float As[16][128];
    int tid = threadIdx.x;
    int j  = tid & 63;
    int nl = tid >> 6;              // 0..3

    for (int g = blockIdx.x; g < NGRP16; g += gridDim.x) {
        int node0 = g * 16;
        const float4* srcp = (const float4*)(A + (size_t)node0 * 128);
        float4* dstp = (float4*)&As[0][0];
        for (int idx = tid; idx < 16 * 128 / 4; idx += 256) dstp[idx] = srcp[idx];
        __syncthreads();

        float acc[4] = {0.f, 0.f, 0.f, 0.f};
#pragma unroll
        for (int k = 0; k < 128; k += 4) {
            float4 a0 = *(const float4*)&As[nl * 4 + 0][k];   // wave-uniform broadcast
            float4 a1 = *(const float4*)&As[nl * 4 + 1][k];
            float4 a2 = *(const float4*)&As[nl * 4 + 2][k];
            float4 a3 = *(const float4*)&As[nl * 4 + 3][k];
            float w0 = W[(k + 0) * 64 + j];
            float w1 = W[(k + 1) * 64 + j];
            float w2 = W[(k + 2) * 64 + j];
            float w3 = W[(k + 3) * 64 + j];
            acc[0] = fmaf(a0.w, w3, fmaf(a0.z, w2, fmaf(a0.y, w1, fmaf(a0.x, w0, acc[0]))));
            acc[1] = fmaf(a1.w, w3, fmaf(a1.z, w2, fmaf(a1.y, w1, fmaf(a1.x, w0, acc[1]))));
            acc[2] = fmaf(a2.w, w3, fmaf(a2.z, w2, fmaf(a2.y, w1, fmaf(a2.x, w0, acc[2]))));
            acc[3] = fmaf(a3.w, w3, fmaf(a3.z, w2, fmaf(a3.y, w1, fmaf(a3.x, w0, acc[3]))));
        }
#pragma unroll
        for (int i = 0; i < 4; i++) {
            int n = node0 + nl * 4 + i;
            hd[(size_t)n * 64 + j] = __float2half(acc[i] * dinv[n]);
        }
        __syncthreads();              // As reused next group
    }
}

// ---------------- agg for one node by one wave: 16 feature-slots x 4 edge-parity ----------------

__device__ __forceinline__ float4 agg_node16(const uint2* __restrict__ hd2,
                                             const int* __restrict__ cnt,
                                             const int* __restrict__ pcur,
                                             const unsigned short* __restrict__ csr16,
                                             int n, int f, int par) {
    int k = pcur[n] + par * 4;
    int iters = (cnt[n] + 15) >> 4;
    float s0 = 0.f, s1 = 0.f, s2 = 0.f, s3 = 0.f;
    for (int it = 0; it < iters; ++it, k += 16) {
        uint2 idx = *(const uint2*)(csr16 + k);           // 4 edge indices (8B)
        int a0 = idx.x & 0xffff, a1 = idx.x >> 16;
        int a2 = idx.y & 0xffff, a3 = idx.y >> 16;
        uint2 r0 = hd2[(size_t)a0 * 16 + f];              // 8B = 4 halves
        uint2 r1 = hd2[(size_t)a1 * 16 + f];
        uint2 r2 = hd2[(size_t)a2 * 16 + f];
        uint2 r3 = hd2[(size_t)a3 * 16 + f];
        float2 p0 = __half22float2(*(const __half2*)&r0.x), q0 = __half22float2(*(const __half2*)&r0.y);
        float2 p1 = __half22float2(*(const __half2*)&r1.x), q1 = __half22float2(*(const __half2*)&r1.y);
        float2 p2 = __half22float2(*(const __half2*)&r2.x), q2 = __half22float2(*(const __half2*)&r2.y);
        float2 p3 = __half22float2(*(const __half2*)&r3.x), q3 = __half22float2(*(const __half2*)&r3.y);
        s0 += (p0.x + p1.x) + (p2.x + p3.x);
        s1 += (p0.y + p1.y) + (p2.y + p3.y);
        s2 += (q0.x + q1.x) + (q2.x + q3.x);
        s3 += (q0.y + q1.y) + (q2.y + q3.y);
    }
    s0 += __shfl_xor(s0, 16, 64); s1 += __shfl_xor(s1, 16, 64);
    s2 += __shfl_xor(s2, 16, 64); s3 += __shfl_xor(s3, 16, 64);
    s0 += __shfl_xor(s0, 32, 64); s1 += __shfl_xor(s1, 32, 64);
    s2 += __shfl_xor(s2, 32, 64); s3 += __shfl_xor(s3, 32, 64);
    return make_float4(s0, s1, s2, s3);
}

// ---------------- fused (persistent): agg(wave=node) + gemm tail(wave0 4-acc) ----------------

__global__ __launch_bounds__(256) void k_fused(const uint2* __restrict__ hd2_in,
                                               const float* __restrict__ b,
                                               const float* __restrict__ dinv,
                                               const int* __restrict__ cnt,
                                               const int* __restrict__ pcur,
                                               const unsigned short* __restrict__ csr16,
                                               const float* __restrict__ W,
                                               __half* __restrict__ hs_out,
                                               __half* __restrict__ hd_out) {
    __shared__ float As[4][64];
    int tid = threadIdx.x;
    int w = tid >> 6, lane = tid & 63;
    int f = lane & 15, par = lane >> 4;

    for (int g = blockIdx.x; g < NGRP4; g += gridDim.x) {
        int node0 = g * 4;
        int n = node0 + w;

        float4 s = agg_node16(hd2_in, cnt, pcur, csr16, n, f, par);
        if (par == 0) {
            float dv = dinv[n];
            uint2 sr = hd2_in[(size_t)n * 16 + f];            // self row (8B)
            float2 sp = __half22float2(*(const __half2*)&sr.x);
            float2 sq = __half22float2(*(const __half2*)&sr.y);
            float o0 = fmaxf(fmaf(s.x + sp.x, dv, b[f * 4 + 0]), 0.f);
            float o1 = fmaxf(fmaf(s.y + sp.y, dv, b[f * 4 + 1]), 0.f);
            float o2 = fmaxf(fmaf(s.z + sq.x, dv, b[f * 4 + 2]), 0.f);
            float o3 = fmaxf(fmaf(s.w + sq.y, dv, b[f * 4 + 3]), 0.f);
            *(float4*)&As[w][f * 4] = make_float4(o0, o1, o2, o3);
            __half2 h0 = __halves2half2(__float2half(o0), __float2half(o1));
            __half2 h1 = __halves2half2(__float2half(o2), __float2half(o3));
            uint2 pk;
            pk.x = *(const unsigned int*)&h0;
            pk.y = *(const unsigned int*)&h1;
            ((uint2*)hs_out)[(size_t)n * 16 + f] = pk;        // 8B store
        }
        __syncthreads();

        // wave 0: gemm for the group's 4 nodes, 4 acc/thread (4x W reuse, ILP 4)
        if (tid < 64) {
            float acc[4] = {0.f, 0.f, 0.f, 0.f};
#pragma unroll
            for (int k = 0; k < 64; k += 4) {
                float4 a0 = *(const float4*)&As[0][k];   // wave-uniform broadcasts
                float4 a1 = *(const float4*)&As[1][k];
                float4 a2 = *(const float4*)&As[2][k];
                float4 a3 = *(const float4*)&As[3][k];
                float w0 = W[(k + 0) * 64 + tid];
                float w1 = W[(k + 1) * 64 + tid];
                float w2 = W[(k + 2) * 64 + tid];
                float w3 = W[(k + 3) * 64 + tid];
                acc[0] = fmaf(a0.w, w3, fmaf(a0.z, w2, fmaf(a0.y, w1, fmaf(a0.x, w0, acc[0]))));
                acc[1] = fmaf(a1.w, w3, fmaf(a1.z, w2, fmaf(a1.y, w1, fmaf(a1.x, w0, acc[1]))));
                acc[2] = fmaf(a2.w, w3, fmaf(a2.z, w2, fmaf(a2.y, w1, fmaf(a2.x, w0, acc[2]))));
                acc[3] = fmaf(a3.w, w3, fmaf(a3.z, w2, fmaf(a3.y, w1, fmaf(a3.x, w0, acc[3]))));
            }
#pragma unroll
            for (int i = 0; i < 4; i++) {
                int nn = node0 + i;
                hd_out[(size_t)nn * 64 + tid] = __float2half(acc[i] * dinv[nn]);
            }
        }
        __syncthreads();              // As reused next group
    }
}

// ---------------- last (persistent): agg + attention + projection(wave0 4-acc) ----------------

__global__ __launch_bounds__(256) void k_last(const uint2* __restrict__ hd2_in,
                                              const float* __restrict__ b,
                                              const float* __restrict__ dinv,
                                              const int* __restrict__ cnt,
                                              const int* __restrict__ pcur,
                                              const unsigned short* __restrict__ csr16,
                                              const __half* __restrict__ hs16,
                                              const float* __restrict__ Wout,
                                              const float* __restrict__ bout,
                                              float* __restrict__ out) {
    __shared__ float As[4][64];
    int tid = threadIdx.x;
    int w = tid >> 6, lane = tid & 63;
    int f = lane & 15, par = lane >> 4;

    for (int g = blockIdx.x; g < NGRP4; g += gridDim.x) {
        int node0 = g * 4;
        int n = node0 + w;

        float4 s = agg_node16(hd2_in, cnt, pcur, csr16, n, f, par);
        if (par == 0) {
            float dv = dinv[n];
            uint2 sr = hd2_in[(size_t)n * 16 + f];
            float2 sp = __half22float2(*(const __half2*)&sr.x);
            float2 sq = __half22float2(*(const __half2*)&sr.y);
            float o0 = fmaxf(fmaf(s.x + sp.x, dv, b[f * 4 + 0]), 0.f);
            float o1 = fmaxf(fmaf(s.y + sp.y, dv, b[f * 4 + 1]), 0.f);
            float o2 = fmaxf(fmaf(s.z + sq.x, dv, b[f * 4 + 2]), 0.f);
            float o3 = fmaxf(fmaf(s.w + sq.y, dv, b[f * 4 + 3]), 0.f);
            *(float4*)&As[w][f * 4] = make_float4(o0, o1, o2, o3);
        }
        __builtin_amdgcn_wave_barrier();

        // attention over layers (wave = node; feature = lane)
        float v[N_LAYER], sc[N_LAYER];
#pragma unroll
        for (int l = 0; l < 3; l++) {
            float val = __half2float(hs16[((size_t)l * N_NODES + n) * 64 + lane]);
            v[l]  = val;
            sc[l] = val * val;
        }
        v[3]  = As[w][lane];
        sc[3] = v[3] * v[3];
#pragma unroll
        for (int off = 32; off > 0; off >>= 1) {
#pragma unroll
            for (int l = 0; l < N_LAYER; l++) sc[l] += __shfl_xor(sc[l], off, 64);
        }
        float m = fmaxf(fmaxf(sc[0], sc[1]), fmaxf(sc[2], sc[3]));
        float e[N_LAYER];
        float sum = 0.f;
#pragma unroll
        for (int l = 0; l < N_LAYER; l++) { e[l] = __expf(sc[l] - m); sum += e[l]; }
        float inv = 1.f / sum;
        float bl = 0.f;
#pragma unroll
        for (int l = 0; l < N_LAYER; l++) bl = fmaf(e[l] * inv, v[l], bl);
        As[w][lane] = bl;                 // own-thread address: ordered after read
        __syncthreads();

        // wave 0: projection for the group's 4 nodes, 4 acc/thread
        if (tid < 64 && tid < N_CLASS) {
            float acc[4] = {bout[tid], bout[tid], bout[tid], bout[tid]};
#pragma unroll
            for (int k = 0; k < 64; k += 4) {
                float4 a0 = *(const float4*)&As[0][k];
                float4 a1 = *(const float4*)&As[1][k];
                float4 a2 = *(const float4*)&As[2][k];
                float4 a3 = *(const float4*)&As[3][k];
                float w0 = Wout[(k + 0) * N_CLASS + tid];
                float w1 = Wout[(k + 1) * N_CLASS + tid];
                float w2 = Wout[(k + 2) * N_CLASS + tid];
                float w3 = Wout[(k + 3) * N_CLASS + tid];
                acc[0] = fmaf(a0.w, w3, fmaf(a0.z, w2, fmaf(a0.y, w1, fmaf(a0.x, w0, acc[0]))));
                acc[1] = fmaf(a1.w, w3, fmaf(a1.z, w2, fmaf(a1.y, w1, fmaf(a1.x, w0, acc[1]))));
                acc[2] = fmaf(a2.w, w3, fmaf(a2.z, w2, fmaf(a2.y, w1, fmaf(a2.x, w0, acc[2]))));
                acc[3] = fmaf(a3.w, w3, fmaf(a3.z, w2, fmaf(a3.y, w1, fmaf(a3.x, w0, acc[3]))));
            }
#pragma unroll
            for (int i = 0; i < 4; i++)
                out[(size_t)(node0 + i) * N_CLASS + tid] = acc[i];
        }
        __syncthreads();              // As reused next group
    }
}

// ---------------- launch ----------------

extern "C" void kernel_launch(void* const* d_in, const int* in_sizes, int n_in,
                              void* d_out, int out_size, void* d_ws, size_t ws_size,
                              hipStream_t stream) {
    const float* x    = (const float*)d_in[0];
    const float* W0   = (const float*)d_in[1];
    const float* b0   = (const float*)d_in[2];
    const float* Ws   = (const float*)d_in[3];
    const float* bs   = (const float*)d_in[4];
    const float* Wout = (const float*)d_in[5];
    const float* bout = (const float*)d_in[6];
    const int*   ei   = (const int*)d_in[7];
    const int* src = ei;
    const int* dst = ei + N_EDGES;
    float* out = (float*)d_out;

    int*            cnt   = (int*)d_ws;                             // N
    int*            pcur  = cnt + N_NODES;                          // N
    int*            bcur  = pcur + N_NODES;                         // NBUCK*BPAD
    float*          dinv  = (float*)(bcur + NBUCK * BPAD);          // N
    unsigned short* csr16 = (unsigned short*)(dinv + N_NODES);      // NBUCK*PBK (x16-pad)
    __half*         hdA   = (__half*)(csr16 + (size_t)NBUCK * PBK); // (N+1)*64
    __half*         hdB   = hdA + (size_t)(N_NODES + 1) * 64;       // (N+1)*64
    __half*         hs16  = hdB + (size_t)(N_NODES + 1) * 64;       // 3*N*64
    unsigned int*   stag  = (unsigned int*)hs16;                    // NBUCK*SCAP, aliased (build only)

    k_zerob <<<1, 256, 0, stream>>>(bcur, hdA, hdB);
    k_bucket<<<NBBLK, 256, 0, stream>>>(src, dst, bcur, stag);
    k_csr2  <<<NBUCK, 256, 0, stream>>>(stag, bcur, cnt, pcur, dinv, csr16);

    k_gemm0<<<PGRID, 256, 0, stream>>>(x, W0, dinv, hdA);

    k_fused<<<PGRID, 256, 0, stream>>>((const uint2*)hdA, b0, dinv, cnt, pcur, csr16,
                                       Ws + 0 * 64 * 64, hs16 + (size_t)0 * N_NODES * 64, hdB);
    k_fused<<<PGRID, 256, 0, stream>>>((const uint2*)hdB, bs + 0 * 64, dinv, cnt, pcur, csr16,
                                       Ws + 1 * 64 * 64, hs16 + (size_t)1 * N_NODES * 64, hdA);
    k_fused<<<PGRID, 256, 0, stream>>>((const uint2*)hdA, bs + 1 * 64, dinv, cnt, pcur, csr16,
                                       Ws + 2 * 64 * 64, hs16 + (size_t)2 * N_NODES * 64, hdB);
    k_last <<<PGRID, 256, 0, stream>>>((const uint2*)hdB, bs + 2 * 64, dinv, cnt, pcur, csr16,
                                       hs16, Wout, bout, out);
}

// Round 16
// 402.819 us; speedup vs baseline: 1.0717x; 1.0717x over previous
//
#include <hip/hip_runtime.h>
#include <hip/hip_fp16.h>

#define N_NODES 50000
#define N_HID   64
#define N_LAYER 4
#define N_CLASS 40
#define N_EDGES 800000

#define BSHIFT 8
#define BSIZE  256                                      // nodes per bucket
#define NBUCK  ((N_NODES + BSIZE - 1) / BSIZE)          // 196
#define BPAD   16                                       // bucket-cursor stride (64B)
#define EPT    16                                       // edges per thread (bucket pass)
#define BKCHUNK (256 * EPT)                             // 4096 edges per block
#define NBBLK  ((N_EDGES + BKCHUNK - 1) / BKCHUNK)      // 196

#define SCAP  5120                                      // fixed stag window per bucket
#define PBK   (SCAP + 15 * BSIZE)                       // 8960: padded (x16) CSR window
#define DUMMY N_NODES                                   // index of zeroed table row

// ---------------- init: bucket cursors + dummy table rows ----------------

__global__ void k_zerob(int* __restrict__ bcur, __half* __restrict__ hdLo,
                        __half* __restrict__ hdHi) {
    int t = threadIdx.x;
    if (t < NBUCK) bcur[t * BPAD] = t * SCAP;
    if (t < 32) {
        hdLo[(size_t)N_NODES * 32 + t] = __float2half(0.f);
        hdHi[(size_t)N_NODES * 32 + t] = __float2half(0.f);
    }
}

// ---------------- block-binned append of packed (dst<<16)|src into fixed bucket windows ----------------

__global__ void k_bucket(const int* __restrict__ src, const int* __restrict__ dst,
                         int* __restrict__ bcur, unsigned int* __restrict__ stag) {
    __shared__ int lhist[NBUCK];
    __shared__ int gbase[NBUCK];
    int t = threadIdx.x;
    for (int i = t; i < NBUCK; i += 256) lhist[i] = 0;
    __syncthreads();

    int base = blockIdx.x * BKCHUNK;
    unsigned int rec[EPT];
    int br[EPT];
#pragma unroll
    for (int i = 0; i < EPT; i++) {
        int e = base + i * 256 + t;      // coalesced
        if (e < N_EDGES) {
            int d = dst[e], s = src[e];
            int b = d >> BSHIFT;
            int r = atomicAdd(&lhist[b], 1);   // in-block rank within bucket
            rec[i] = ((unsigned int)d << 16) | (unsigned int)s;
            br[i]  = (b << 16) | r;            // r < 4096
        } else {
            br[i] = -1;
        }
    }
    __syncthreads();
    for (int i = t; i < NBUCK; i += 256) {
        int c = lhist[i];
        gbase[i] = c ? atomicAdd(&bcur[i * BPAD], c) : 0;
    }
    __syncthreads();
#pragma unroll
    for (int i = 0; i < EPT; i++) {
        if (br[i] >= 0) {
            int b = br[i] >> 16, r = br[i] & 0xffff;
            stag[gbase[b] + r] = rec[i];
        }
    }
}

// ---------------- per-bucket: LDS count + scan -> CSR rows padded to x16 ----------------

__global__ void k_csr2(const unsigned int* __restrict__ stag, const int* __restrict__ bcur,
                       int* __restrict__ cnt, int* __restrict__ pcurg,
                       float* __restrict__ dinv, unsigned short* __restrict__ csr16) {
    __shared__ int lcnt[BSIZE], ltmp[BSIZE], lcur[BSIZE];
    int b = blockIdx.x, t = threadIdx.x;
    int bstart = b * SCAP;
    int bend   = bcur[b * BPAD];         // post-append cursor = bucket end
    lcnt[t] = 0;
    __syncthreads();
    for (int i = bstart + t; i < bend; i += 256)
        atomicAdd(&lcnt[(stag[i] >> 16) & (BSIZE - 1)], 1);
    __syncthreads();
    int v = lcnt[t];
    int p = (v + 15) & ~15;              // padded row size (x16)
    ltmp[t] = p;
    __syncthreads();
    for (int off = 1; off < 256; off <<= 1) {
        int u = (t >= off) ? ltmp[t - off] : 0;
        __syncthreads();
        ltmp[t] += u;
        __syncthreads();
    }
    int pstart = b * PBK + ltmp[t] - p;  // node's padded CSR row start (x16 aligned)
    lcur[t] = pstart;
    int node = (b << BSHIFT) + t;
    if (node < N_NODES) {
        cnt[node]   = v;
        pcurg[node] = pstart;
        dinv[node]  = rsqrtf((float)(v + 1));
    }
    __syncthreads();
    for (int i = bstart + t; i < bend; i += 256) {
        unsigned int rec = stag[i];
        int pos = atomicAdd(&lcur[(rec >> 16) & (BSIZE - 1)], 1);
        csr16[pos] = (unsigned short)rec;
    }
    for (int i = v; i < p; i++)          // fill pad slots with dummy zero-row
        csr16[pstart + i] = (unsigned short)DUMMY;
}

// ---------------- layer-0 GEMM (tiled, 4 acc/thread): hdLo/hdHi = half((x@W0)*dinv) ----------------

__global__ __launch_bounds__(256) void k_gemm0(const float* __restrict__ A,
                                               const float* __restrict__ W,
                                               const float* __restrict__ dinv,
                                               __half* __restrict__ hdLo,
                                               __half* __restrict__ hdHi) {
    __shared__ float As[16][128];
    int tid = threadIdx.x;
    int j  = tid & 63;
    int nl = tid >> 6;              // 0..3
    int node0 = blockIdx.x * 16;

    const float4* srcp = (const float4*)(A + (size_t)node0 * 128);
    float4* dstp = (float4*)&As[0][0];
    for (int idx = tid; idx < 16 * 128 / 4; idx += 256) dstp[idx] = srcp[idx];
    __syncthreads();

    float acc[4] = {0.f, 0.f, 0.f, 0.f};
#pragma unroll
    for (int k = 0; k < 128; k += 4) {
        float4 a0 = *(const float4*)&As[nl * 4 + 0][k];   // wave-uniform broadcast
        float4 a1 = *(const float4*)&As[nl * 4 + 1][k];
        float4 a2 = *(const float4*)&As[nl * 4 + 2][k];
        float4 a3 = *(const float4*)&As[nl * 4 + 3][k];
        float w0 = W[(k + 0) * 64 + j];
        float w1 = W[(k + 1) * 64 + j];
        float w2 = W[(k + 2) * 64 + j];
        float w3 = W[(k + 3) * 64 + j];
        acc[0] = fmaf(a0.w, w3, fmaf(a0.z, w2, fmaf(a0.y, w1, fmaf(a0.x, w0, acc[0]))));
        acc[1] = fmaf(a1.w, w3, fmaf(a1.z, w2, fmaf(a1.y, w1, fmaf(a1.x, w0, acc[1]))));
        acc[2] = fmaf(a2.w, w3, fmaf(a2.z, w2, fmaf(a2.y, w1, fmaf(a2.x, w0, acc[2]))));
        acc[3] = fmaf(a3.w, w3, fmaf(a3.z, w2, fmaf(a3.y, w1, fmaf(a3.x, w0, acc[3]))));
    }
#pragma unroll
    for (int i = 0; i < 4; i++) {
        int n = node0 + nl * 4 + i;
        float v = acc[i] * dinv[n];
        if (j < 32) hdLo[(size_t)n * 32 + j]      = __float2half(v);
        else        hdHi[(size_t)n * 32 + j - 32] = __float2half(v);
    }
}

// ---------------- agg half-pass: gather from a 3.2MB (L2-resident) table ----------------
// wave = node: 8 feature-slots (8B each) x 8 edge-parity groups -> 16 edges/iter.
// Finalizes: hs = relu((sum + self)*dinv + b) for this 32-feature half.

__global__ __launch_bounds__(256) void k_agg(const uint2* __restrict__ tbl,
                                             const float* __restrict__ b32,
                                             const float* __restrict__ dinv,
                                             const int* __restrict__ cnt,
                                             const int* __restrict__ pcur,
                                             const unsigned short* __restrict__ csr16,
                                             uint2* __restrict__ hs_out) {
    int tid = threadIdx.x;
    int w = tid >> 6, lane = tid & 63;
    int f = lane & 7;            // feature slot (4 features)
    int par = lane >> 3;         // edge parity 0..7
    int n = blockIdx.x * 4 + w;

    int k = pcur[n] + par * 2;
    int iters = (cnt[n] + 15) >> 4;
    float s0 = 0.f, s1 = 0.f, s2 = 0.f, s3 = 0.f;
    for (int it = 0; it < iters; ++it, k += 16) {
        unsigned int idx = *(const unsigned int*)(csr16 + k);   // 2 edge indices (4B)
        int a0 = idx & 0xffff, a1 = idx >> 16;
        uint2 r0 = tbl[(size_t)a0 * 8 + f];                     // 8B = 4 halves
        uint2 r1 = tbl[(size_t)a1 * 8 + f];
        float2 p0 = __half22float2(*(const __half2*)&r0.x), q0 = __half22float2(*(const __half2*)&r0.y);
        float2 p1 = __half22float2(*(const __half2*)&r1.x), q1 = __half22float2(*(const __half2*)&r1.y);
        s0 += p0.x + p1.x;
        s1 += p0.y + p1.y;
        s2 += q0.x + q1.x;
        s3 += q0.y + q1.y;
    }
    // reduce over the 8 parity groups (lane bits 3,4,5)
    s0 += __shfl_xor(s0, 8, 64);  s1 += __shfl_xor(s1, 8, 64);
    s2 += __shfl_xor(s2, 8, 64);  s3 += __shfl_xor(s3, 8, 64);
    s0 += __shfl_xor(s0, 16, 64); s1 += __shfl_xor(s1, 16, 64);
    s2 += __shfl_xor(s2, 16, 64); s3 += __shfl_xor(s3, 16, 64);
    s0 += __shfl_xor(s0, 32, 64); s1 += __shfl_xor(s1, 32, 64);
    s2 += __shfl_xor(s2, 32, 64); s3 += __shfl_xor(s3, 32, 64);

    if (par == 0) {
        float dv = dinv[n];
        uint2 sr = tbl[(size_t)n * 8 + f];                      // self row (8B)
        float2 sp = __half22float2(*(const __half2*)&sr.x);
        float2 sq = __half22float2(*(const __half2*)&sr.y);
        float o0 = fmaxf(fmaf(s0 + sp.x, dv, b32[f * 4 + 0]), 0.f);
        float o1 = fmaxf(fmaf(s1 + sp.y, dv, b32[f * 4 + 1]), 0.f);
        float o2 = fmaxf(fmaf(s2 + sq.x, dv, b32[f * 4 + 2]), 0.f);
        float o3 = fmaxf(fmaf(s3 + sq.y, dv, b32[f * 4 + 3]), 0.f);
        __half2 h0 = __halves2half2(__float2half(o0), __float2half(o1));
        __half2 h1 = __halves2half2(__float2half(o2), __float2half(o3));
        uint2 pk;
        pk.x = *(const unsigned int*)&h0;
        pk.y = *(const unsigned int*)&h1;
        hs_out[(size_t)n * 16 + f] = pk;                        // 8B store
    }
}

// ---------------- mid-layer GEMM: reads fp16 hs, writes hdLo/hdHi ----------------

__global__ __launch_bounds__(256) void k_gemm(const uint2* __restrict__ hs,
                                              const float* __restrict__ W,
                                              const float* __restrict__ dinv,
                                              __half* __restrict__ hdLo,
                                              __half* __restrict__ hdHi) {
    __shared__ float As[16][64];
    int tid = threadIdx.x;
    int node0 = blockIdx.x * 16;

    uint2 h = hs[(size_t)node0 * 16 + tid];          // 16 rows x 16 uint2 = 256 loads
    float2 pa = __half22float2(*(const __half2*)&h.x);
    float2 pb = __half22float2(*(const __half2*)&h.y);
    *(float4*)&As[tid >> 4][(tid & 15) * 4] = make_float4(pa.x, pa.y, pb.x, pb.y);
    __syncthreads();

    int j  = tid & 63;
    int nl = tid >> 6;
    float acc[4] = {0.f, 0.f, 0.f, 0.f};
#pragma unroll
    for (int k = 0; k < 64; k += 4) {
        float4 a0 = *(const float4*)&As[nl * 4 + 0][k];
        float4 a1 = *(const float4*)&As[nl * 4 + 1][k];
        float4 a2 = *(const float4*)&As[nl * 4 + 2][k];
        float4 a3 = *(const float4*)&As[nl * 4 + 3][k];
        float w0 = W[(k + 0) * 64 + j];
        float w1 = W[(k + 1) * 64 + j];
        float w2 = W[(k + 2) * 64 + j];
        float w3 = W[(k + 3) * 64 + j];
        acc[0] = fmaf(a0.w, w3, fmaf(a0.z, w2, fmaf(a0.y, w1, fmaf(a0.x, w0, acc[0]))));
        acc[1] = fmaf(a1.w, w3, fmaf(a1.z, w2, fmaf(a1.y, w1, fmaf(a1.x, w0, acc[1]))));
        acc[2] = fmaf(a2.w, w3, fmaf(a2.z, w2, fmaf(a2.y, w1, fmaf(a2.x, w0, acc[2]))));
        acc[3] = fmaf(a3.w, w3, fmaf(a3.z, w2, fmaf(a3.y, w1, fmaf(a3.x, w0, acc[3]))));
    }
#pragma unroll
    for (int i = 0; i < 4; i++) {
        int n = node0 + nl * 4 + i;
        float v = acc[i] * dinv[n];
        if (j < 32) hdLo[(size_t)n * 32 + j]      = __float2half(v);
        else        hdHi[(size_t)n * 32 + j - 32] = __float2half(v);
    }
}

// ---------------- attention over layers + output projection (fp16 hs, 4 layers) ----------------

__global__ __launch_bounds__(256) void k_attn(const __half* __restrict__ hs16,
                                              const float* __restrict__ Wout,
                                              const float* __restrict__ bout,
                                              float* __restrict__ out) {
    __shared__ float blend[4][64];
    int j  = threadIdx.x & 63;
    int nl = threadIdx.x >> 6;
    int n  = blockIdx.x * 4 + nl;

    float v[N_LAYER], sc[N_LAYER];
#pragma unroll
    for (int l = 0; l < N_LAYER; l++) {
        float val = __half2float(hs16[((size_t)l * N_NODES + n) * 64 + j]);
        v[l]  = val;
        sc[l] = val * val;
    }
#pragma unroll
    for (int off = 32; off > 0; off >>= 1) {
#pragma unroll
        for (int l = 0; l < N_LAYER; l++) sc[l] += __shfl_xor(sc[l], off, 64);
    }
    float m = fmaxf(fmaxf(sc[0], sc[1]), fmaxf(sc[2], sc[3]));
    float e[N_LAYER];
    float sum = 0.f;
#pragma unroll
    for (int l = 0; l < N_LAYER; l++) { e[l] = __expf(sc[l] - m); sum += e[l]; }
    float inv = 1.f / sum;
    float bl = 0.f;
#pragma unroll
    for (int l = 0; l < N_LAYER; l++) bl = fmaf(e[l] * inv, v[l], bl);
    blend[nl][j] = bl;
    __syncthreads();

    if (j < N_CLASS) {
        float o = bout[j];
#pragma unroll
        for (int k = 0; k < 64; k++)
            o = fmaf(blend[nl][k], Wout[k * N_CLASS + j], o);
        out[(size_t)n * N_CLASS + j] = o;
    }
}

// ---------------- launch ----------------

extern "C" void kernel_launch(void* const* d_in, const int* in_sizes, int n_in,
                              void* d_out, int out_size, void* d_ws, size_t ws_size,
                              hipStream_t stream) {
    const float* x    = (const float*)d_in[0];
    const float* W0   = (const float*)d_in[1];
    const float* b0   = (const float*)d_in[2];
    const float* Ws   = (const float*)d_in[3];
    const float* bs   = (const float*)d_in[4];
    const float* Wout = (const float*)d_in[5];
    const float* bout = (const float*)d_in[6];
    const int*   ei   = (const int*)d_in[7];
    const int* src = ei;
    const int* dst = ei + N_EDGES;
    float* out = (float*)d_out;

    int*            cnt   = (int*)d_ws;                             // N
    int*            pcur  = cnt + N_NODES;                          // N
    int*            bcur  = pcur + N_NODES;                         // NBUCK*BPAD
    float*          dinv  = (float*)(bcur + NBUCK * BPAD);          // N
    unsigned short* csr16 = (unsigned short*)(dinv + N_NODES);      // NBUCK*PBK (x16-pad)
    __half*         hdLo  = (__half*)(csr16 + (size_t)NBUCK * PBK); // (N+1)*32  (3.2MB table)
    __half*         hdHi  = hdLo + (size_t)(N_NODES + 1) * 32;      // (N+1)*32  (3.2MB table)
    __half*         hs16  = hdHi + (size_t)(N_NODES + 1) * 32;      // 4*N*64
    unsigned int*   stag  = (unsigned int*)hs16;                    // NBUCK*SCAP, aliased (build only)

    k_zerob <<<1, 256, 0, stream>>>(bcur, hdLo, hdHi);
    k_bucket<<<NBBLK, 256, 0, stream>>>(src, dst, bcur, stag);
    k_csr2  <<<NBUCK, 256, 0, stream>>>(stag, bcur, cnt, pcur, dinv, csr16);

    k_gemm0<<<N_NODES / 16, 256, 0, stream>>>(x, W0, dinv, hdLo, hdHi);

    const int NB = N_NODES / 4;   // 12500 blocks, wave = node (agg / attn)

    for (int l = 0; l < N_LAYER; l++) {
        const float* b = (l == 0) ? b0 : bs + (size_t)(l - 1) * 64;
        __half* hs_l = hs16 + (size_t)l * N_NODES * 64;
        // lo half: table hdLo is L2-resident (3.2MB per XCD)
        k_agg<<<NB, 256, 0, stream>>>((const uint2*)hdLo, b, dinv, cnt, pcur, csr16,
                                      (uint2*)hs_l + 0);
        // hi half
        k_agg<<<NB, 256, 0, stream>>>((const uint2*)hdHi, b + 32, dinv, cnt, pcur, csr16,
                                      (uint2*)hs_l + 8);
        if (l < N_LAYER - 1)
            k_gemm<<<N_NODES / 16, 256, 0, stream>>>((const uint2*)hs_l,
                                                     Ws + (size_t)l * 64 * 64, dinv,
                                                     hdLo, hdHi);
    }

    k_attn<<<NB, 256, 0, stream>>>(hs16, Wout, bout, out);
}

// Round 17
// 213.452 us; speedup vs baseline: 2.0225x; 1.8872x over previous
//
#include <hip/hip_runtime.h>
#include <hip/hip_fp16.h>

#define N_NODES 50000
#define N_HID   64
#define N_LAYER 4
#define N_CLASS 40
#define N_EDGES 800000

#define BSHIFT 8
#define BSIZE  256                                      // nodes per bucket
#define NBUCK  ((N_NODES + BSIZE - 1) / BSIZE)          // 196
#define BPAD   16                                       // bucket-cursor stride (64B)
#define EPT    16                                       // edges per thread (bucket pass)
#define BKCHUNK (256 * EPT)                             // 4096 edges per block
#define NBBLK  ((N_EDGES + BKCHUNK - 1) / BKCHUNK)      // 196

#define SCAP  5120                                      // fixed stag window per bucket
#define PBK   (SCAP + 15 * BSIZE)                       // 8960: padded (x16) CSR window
#define DUMMY N_NODES                                   // index of zeroed hd row

// ---------------- init: bucket cursors + dummy hd rows ----------------

__global__ void k_zerob(int* __restrict__ bcur, __half* __restrict__ hdA,
                        __half* __restrict__ hdB) {
    int t = threadIdx.x;
    if (t < NBUCK) bcur[t * BPAD] = t * SCAP;
    if (t < 64) {
        hdA[(size_t)N_NODES * 64 + t] = __float2half(0.f);
        hdB[(size_t)N_NODES * 64 + t] = __float2half(0.f);
    }
}

// ---------------- block-binned append of packed (dst<<16)|src into fixed bucket windows ----------------

__global__ void k_bucket(const int* __restrict__ src, const int* __restrict__ dst,
                         int* __restrict__ bcur, unsigned int* __restrict__ stag) {
    __shared__ int lhist[NBUCK];
    __shared__ int gbase[NBUCK];
    int t = threadIdx.x;
    for (int i = t; i < NBUCK; i += 256) lhist[i] = 0;
    __syncthreads();

    int base = blockIdx.x * BKCHUNK;
    unsigned int rec[EPT];
    int br[EPT];
#pragma unroll
    for (int i = 0; i < EPT; i++) {
        int e = base + i * 256 + t;      // coalesced
        if (e < N_EDGES) {
            int d = dst[e], s = src[e];
            int b = d >> BSHIFT;
            int r = atomicAdd(&lhist[b], 1);   // in-block rank within bucket
            rec[i] = ((unsigned int)d << 16) | (unsigned int)s;
            br[i]  = (b << 16) | r;            // r < 4096
        } else {
            br[i] = -1;
        }
    }
    __syncthreads();
    for (int i = t; i < NBUCK; i += 256) {
        int c = lhist[i];
        gbase[i] = c ? atomicAdd(&bcur[i * BPAD], c) : 0;
    }
    __syncthreads();
#pragma unroll
    for (int i = 0; i < EPT; i++) {
        if (br[i] >= 0) {
            int b = br[i] >> 16, r = br[i] & 0xffff;
            stag[gbase[b] + r] = rec[i];
        }
    }
}

// ---------------- per-bucket: LDS count + scan -> CSR rows padded to x16 ----------------

__global__ void k_csr2(const unsigned int* __restrict__ stag, const int* __restrict__ bcur,
                       int* __restrict__ cnt, int* __restrict__ pcurg,
                       float* __restrict__ dinv, unsigned short* __restrict__ csr16) {
    __shared__ int lcnt[BSIZE], ltmp[BSIZE], lcur[BSIZE];
    int b = blockIdx.x, t = threadIdx.x;
    int bstart = b * SCAP;
    int bend   = bcur[b * BPAD];         // post-append cursor = bucket end
    lcnt[t] = 0;
    __syncthreads();
    for (int i = bstart + t; i < bend; i += 256)
        atomicAdd(&lcnt[(stag[i] >> 16) & (BSIZE - 1)], 1);
    __syncthreads();
    int v = lcnt[t];
    int p = (v + 15) & ~15;              // padded row size (x16)
    ltmp[t] = p;
    __syncthreads();
    for (int off = 1; off < 256; off <<= 1) {
        int u = (t >= off) ? ltmp[t - off] : 0;
        __syncthreads();
        ltmp[t] += u;
        __syncthreads();
    }
    int pstart = b * PBK + ltmp[t] - p;  // node's padded CSR row start (x16 aligned)
    lcur[t] = pstart;
    int node = (b << BSHIFT) + t;
    if (node < N_NODES) {
        cnt[node]   = v;
        pcurg[node] = pstart;
        dinv[node]  = rsqrtf((float)(v + 1));
    }
    __syncthreads();
    for (int i = bstart + t; i < bend; i += 256) {
        unsigned int rec = stag[i];
        int pos = atomicAdd(&lcur[(rec >> 16) & (BSIZE - 1)], 1);
        csr16[pos] = (unsigned short)rec;
    }
    for (int i = v; i < p; i++)          // fill pad slots with dummy zero-row
        csr16[pstart + i] = (unsigned short)DUMMY;
}

// ---------------- layer-0 GEMM (tiled, 4 acc/thread): hd = half((x@W0)*dinv) ----------------
// Byte-identical to round 12 (known-good: ~40 VGPR, ~14us).

__global__ __launch_bounds__(256) void k_gemm0(const float* __restrict__ A,
                                               const float* __restrict__ W,
                                               const float* __restrict__ dinv,
                                               __half* __restrict__ hd) {
    __shared__ float As[16][128];
    int tid = threadIdx.x;
    int j  = tid & 63;
    int nl = tid >> 6;              // 0..3
    int node0 = blockIdx.x * 16;

    const float4* srcp = (const float4*)(A + (size_t)node0 * 128);
    float4* dstp = (float4*)&As[0][0];
    for (int idx = tid; idx < 16 * 128 / 4; idx += 256) dstp[idx] = srcp[idx];
    __syncthreads();

    float acc[4] = {0.f, 0.f, 0.f, 0.f};
#pragma unroll
    for (int k = 0; k < 128; k += 4) {
        float4 a0 = *(const float4*)&As[nl * 4 + 0][k];   // wave-uniform broadcast
        float4 a1 = *(const float4*)&As[nl * 4 + 1][k];
        float4 a2 = *(const float4*)&As[nl * 4 + 2][k];
        float4 a3 = *(const float4*)&As[nl * 4 + 3][k];
        float w0 = W[(k + 0) * 64 + j];
        float w1 = W[(k + 1) * 64 + j];
        float w2 = W[(k + 2) * 64 + j];
        float w3 = W[(k + 3) * 64 + j];
        acc[0] = fmaf(a0.w, w3, fmaf(a0.z, w2, fmaf(a0.y, w1, fmaf(a0.x, w0, acc[0]))));
        acc[1] = fmaf(a1.w, w3, fmaf(a1.z, w2, fmaf(a1.y, w1, fmaf(a1.x, w0, acc[1]))));
        acc[2] = fmaf(a2.w, w3, fmaf(a2.z, w2, fmaf(a2.y, w1, fmaf(a2.x, w0, acc[2]))));
        acc[3] = fmaf(a3.w, w3, fmaf(a3.z, w2, fmaf(a3.y, w1, fmaf(a3.x, w0, acc[3]))));
    }
#pragma unroll
    for (int i = 0; i < 4; i++) {
        int n = node0 + nl * 4 + i;
        hd[(size_t)n * 64 + j] = __float2half(acc[i] * dinv[n]);
    }
}

// ---------------- standalone agg: wave=node, no LDS, no barriers ----------------
// 16 feature-slots (8B) x 4 edge-parity; writes fp16 hs row directly.

__global__ __launch_bounds__(256) void k_agg(const uint2* __restrict__ hd2_in,
                                             const float* __restrict__ b,
                                             const float* __restrict__ dinv,
                                             const int* __restrict__ cnt,
                                             const int* __restrict__ pcur,
                                             const unsigned short* __restrict__ csr16,
                                             uint2* __restrict__ hs_out) {
    int tid = threadIdx.x;
    int w = tid >> 6, lane = tid & 63;
    int f = lane & 15, par = lane >> 4;
    int n = blockIdx.x * 4 + w;

    int k = pcur[n] + par * 4;
    int iters = (cnt[n] + 15) >> 4;
    float s0 = 0.f, s1 = 0.f, s2 = 0.f, s3 = 0.f;
    for (int it = 0; it < iters; ++it, k += 16) {
        uint2 idx = *(const uint2*)(csr16 + k);           // 4 edge indices (8B)
        int a0 = idx.x & 0xffff, a1 = idx.x >> 16;
        int a2 = idx.y & 0xffff, a3 = idx.y >> 16;
        uint2 r0 = hd2_in[(size_t)a0 * 16 + f];           // 8B = 4 halves
        uint2 r1 = hd2_in[(size_t)a1 * 16 + f];
        uint2 r2 = hd2_in[(size_t)a2 * 16 + f];
        uint2 r3 = hd2_in[(size_t)a3 * 16 + f];
        float2 p0 = __half22float2(*(const __half2*)&r0.x), q0 = __half22float2(*(const __half2*)&r0.y);
        float2 p1 = __half22float2(*(const __half2*)&r1.x), q1 = __half22float2(*(const __half2*)&r1.y);
        float2 p2 = __half22float2(*(const __half2*)&r2.x), q2 = __half22float2(*(const __half2*)&r2.y);
        float2 p3 = __half22float2(*(const __half2*)&r3.x), q3 = __half22float2(*(const __half2*)&r3.y);
        s0 += (p0.x + p1.x) + (p2.x + p3.x);
        s1 += (p0.y + p1.y) + (p2.y + p3.y);
        s2 += (q0.x + q1.x) + (q2.x + q3.x);
        s3 += (q0.y + q1.y) + (q2.y + q3.y);
    }
    s0 += __shfl_xor(s0, 16, 64); s1 += __shfl_xor(s1, 16, 64);
    s2 += __shfl_xor(s2, 16, 64); s3 += __shfl_xor(s3, 16, 64);
    s0 += __shfl_xor(s0, 32, 64); s1 += __shfl_xor(s1, 32, 64);
    s2 += __shfl_xor(s2, 32, 64); s3 += __shfl_xor(s3, 32, 64);

    if (par == 0) {
        float dv = dinv[n];
        uint2 sr = hd2_in[(size_t)n * 16 + f];            // self row (8B)
        float2 sp = __half22float2(*(const __half2*)&sr.x);
        float2 sq = __half22float2(*(const __half2*)&sr.y);
        float o0 = fmaxf(fmaf(s0 + sp.x, dv, b[f * 4 + 0]), 0.f);
        float o1 = fmaxf(fmaf(s1 + sp.y, dv, b[f * 4 + 1]), 0.f);
        float o2 = fmaxf(fmaf(s2 + sq.x, dv, b[f * 4 + 2]), 0.f);
        float o3 = fmaxf(fmaf(s3 + sq.y, dv, b[f * 4 + 3]), 0.f);
        __half2 h0 = __halves2half2(__float2half(o0), __float2half(o1));
        __half2 h1 = __halves2half2(__float2half(o2), __float2half(o3));
        uint2 pk;
        pk.x = *(const unsigned int*)&h0;
        pk.y = *(const unsigned int*)&h1;
        hs_out[(size_t)n * 16 + f] = pk;                  // 8B store
    }
}

// ---------------- mid-layer GEMM: reads fp16 hs, writes fp16 hd (single buffer) ----------------

__global__ __launch_bounds__(256) void k_gemm(const uint2* __restrict__ hs,
                                              const float* __restrict__ W,
                                              const float* __restrict__ dinv,
                                              __half* __restrict__ hd_out) {
    __shared__ float As[16][64];
    int tid = threadIdx.x;
    int node0 = blockIdx.x * 16;

    uint2 h = hs[(size_t)node0 * 16 + tid];          // 16 rows x 16 uint2, coalesced
    float2 pa = __half22float2(*(const __half2*)&h.x);
    float2 pb = __half22float2(*(const __half2*)&h.y);
    *(float4*)&As[tid >> 4][(tid & 15) * 4] = make_float4(pa.x, pa.y, pb.x, pb.y);
    __syncthreads();

    int j  = tid & 63;
    int nl = tid >> 6;
    float acc[4] = {0.f, 0.f, 0.f, 0.f};
#pragma unroll
    for (int k = 0; k < 64; k += 4) {
        float4 a0 = *(const float4*)&As[nl * 4 + 0][k];
        float4 a1 = *(const float4*)&As[nl * 4 + 1][k];
        float4 a2 = *(const float4*)&As[nl * 4 + 2][k];
        float4 a3 = *(const float4*)&As[nl * 4 + 3][k];
        float w0 = W[(k + 0) * 64 + j];
        float w1 = W[(k + 1) * 64 + j];
        float w2 = W[(k + 2) * 64 + j];
        float w3 = W[(k + 3) * 64 + j];
        acc[0] = fmaf(a0.w, w3, fmaf(a0.z, w2, fmaf(a0.y, w1, fmaf(a0.x, w0, acc[0]))));
        acc[1] = fmaf(a1.w, w3, fmaf(a1.z, w2, fmaf(a1.y, w1, fmaf(a1.x, w0, acc[1]))));
        acc[2] = fmaf(a2.w, w3, fmaf(a2.z, w2, fmaf(a2.y, w1, fmaf(a2.x, w0, acc[2]))));
        acc[3] = fmaf(a3.w, w3, fmaf(a3.z, w2, fmaf(a3.y, w1, fmaf(a3.x, w0, acc[3]))));
    }
#pragma unroll
    for (int i = 0; i < 4; i++) {
        int n = node0 + nl * 4 + i;
        hd_out[(size_t)n * 64 + j] = __float2half(acc[i] * dinv[n]);
    }
}

// ---------------- attention over layers + output projection (all-fp16 hs) ----------------

__global__ __launch_bounds__(256) void k_attn(const __half* __restrict__ hs16,
                                              const float* __restrict__ Wout,
                                              const float* __restrict__ bout,
                                              float* __restrict__ out) {
    __shared__ float blend[4][64];
    int j  = threadIdx.x & 63;
    int nl = threadIdx.x >> 6;
    int n  = blockIdx.x * 4 + nl;

    float v[N_LAYER], sc[N_LAYER];
#pragma unroll
    for (int l = 0; l < N_LAYER; l++) {
        float val = __half2float(hs16[((size_t)l * N_NODES + n) * 64 + j]);
        v[l]  = val;
        sc[l] = val * val;
    }
#pragma unroll
    for (int off = 32; off > 0; off >>= 1) {
#pragma unroll
        for (int l = 0; l < N_LAYER; l++) sc[l] += __shfl_xor(sc[l], off, 64);
    }
    float m = fmaxf(fmaxf(sc[0], sc[1]), fmaxf(sc[2], sc[3]));
    float e[N_LAYER];
    float sum = 0.f;
#pragma unroll
    for (int l = 0; l < N_LAYER; l++) { e[l] = __expf(sc[l] - m); sum += e[l]; }
    float inv = 1.f / sum;
    float bl = 0.f;
#pragma unroll
    for (int l = 0; l < N_LAYER; l++) bl = fmaf(e[l] * inv, v[l], bl);
    blend[nl][j] = bl;
    __syncthreads();

    if (j < N_CLASS) {
        float o = bout[j];
#pragma unroll
        for (int k = 0; k < 64; k++)
            o = fmaf(blend[nl][k], Wout[k * N_CLASS + j], o);
        out[(size_t)n * N_CLASS + j] = o;
    }
}

// ---------------- launch ----------------

extern "C" void kernel_launch(void* const* d_in, const int* in_sizes, int n_in,
                              void* d_out, int out_size, void* d_ws, size_t ws_size,
                              hipStream_t stream) {
    const float* x    = (const float*)d_in[0];
    const float* W0   = (const float*)d_in[1];
    const float* b0   = (const float*)d_in[2];
    const float* Ws   = (const float*)d_in[3];
    const float* bs   = (const float*)d_in[4];
    const float* Wout = (const float*)d_in[5];
    const float* bout = (const float*)d_in[6];
    const int*   ei   = (const int*)d_in[7];
    const int* src = ei;
    const int* dst = ei + N_EDGES;
    float* out = (float*)d_out;

    int*            cnt   = (int*)d_ws;                             // N
    int*            pcur  = cnt + N_NODES;                          // N
    int*            bcur  = pcur + N_NODES;                         // NBUCK*BPAD
    float*          dinv  = (float*)(bcur + NBUCK * BPAD);          // N
    unsigned short* csr16 = (unsigned short*)(dinv + N_NODES);      // NBUCK*PBK (x16-pad)
    __half*         hdA   = (__half*)(csr16 + (size_t)NBUCK * PBK); // (N+1)*64
    __half*         hdB   = hdA + (size_t)(N_NODES + 1) * 64;       // (N+1)*64
    __half*         hs16  = hdB + (size_t)(N_NODES + 1) * 64;       // 4*N*64
    unsigned int*   stag  = (unsigned int*)hs16;                    // NBUCK*SCAP, aliased (build only)

    k_zerob <<<1, 256, 0, stream>>>(bcur, hdA, hdB);
    k_bucket<<<NBBLK, 256, 0, stream>>>(src, dst, bcur, stag);
    k_csr2  <<<NBUCK, 256, 0, stream>>>(stag, bcur, cnt, pcur, dinv, csr16);

    k_gemm0<<<N_NODES / 16, 256, 0, stream>>>(x, W0, dinv, hdA);

    const int NB = N_NODES / 4;    // 12500 blocks, wave = node
    const int NG = N_NODES / 16;   // 3125 blocks, tiled gemm

    __half* hd_in = hdA;
    __half* hd_ot = hdB;
    for (int l = 0; l < N_LAYER; l++) {
        const float* b = (l == 0) ? b0 : bs + (size_t)(l - 1) * 64;
        __half* hs_l = hs16 + (size_t)l * N_NODES * 64;
        k_agg<<<NB, 256, 0, stream>>>((const uint2*)hd_in, b, dinv, cnt, pcur, csr16,
                                      (uint2*)hs_l);
        if (l < N_LAYER - 1) {
            k_gemm<<<NG, 256, 0, stream>>>((const uint2*)hs_l,
                                           Ws + (size_t)l * 64 * 64, dinv, hd_ot);
            __half* tmp = hd_in; hd_in = hd_ot; hd_ot = tmp;
        }
    }

    k_attn<<<NB, 256, 0, stream>>>(hs16, Wout, bout, out);
}

// Round 18
// 186.542 us; speedup vs baseline: 2.3142x; 1.1443x over previous
//
#include <hip/hip_runtime.h>
#include <hip/hip_fp16.h>

#define N_NODES 50000
#define N_HID   64
#define N_LAYER 4
#define N_CLASS 40
#define N_EDGES 800000

#define BSHIFT 8
#define BSIZE  256                                      // nodes per bucket
#define NBUCK  ((N_NODES + BSIZE - 1) / BSIZE)          // 196
#define BPAD   16                                      // bucket-cursor stride (64B)
#define EPT    16                                      // edges per thread (bucket pass)
#define BKCHUNK (256 * EPT)                             // 4096 edges per block
#define NBBLK  ((N_EDGES + BKCHUNK - 1) / BKCHUNK)      // 196

#define SCAP  5120                                      // fixed stag window per bucket
                                                        // (mean 4082, sd 64 -> +16 sigma)
#define PBK   (SCAP + 7 * BSIZE)                        // 6912: padded CSR window
#define DUMMY N_NODES                                   // index of zeroed hd row

// ---------------- init: bucket cursors + dummy hd rows ----------------

__global__ void k_zerob(int* __restrict__ bcur, __half* __restrict__ hdA,
                        __half* __restrict__ hdB) {
    int t = threadIdx.x;
    if (t < NBUCK) bcur[t * BPAD] = t * SCAP;
    if (t < 64) {
        hdA[(size_t)N_NODES * 64 + t] = __float2half(0.f);
        hdB[(size_t)N_NODES * 64 + t] = __float2half(0.f);
    }
}

// ---------------- block-binned append of packed (dst<<16)|src into fixed bucket windows ----------------

__global__ void k_bucket(const int* __restrict__ src, const int* __restrict__ dst,
                         int* __restrict__ bcur, unsigned int* __restrict__ stag) {
    __shared__ int lhist[NBUCK];
    __shared__ int gbase[NBUCK];
    int t = threadIdx.x;
    for (int i = t; i < NBUCK; i += 256) lhist[i] = 0;
    __syncthreads();

    int base = blockIdx.x * BKCHUNK;
    unsigned int rec[EPT];
    int br[EPT];
#pragma unroll
    for (int i = 0; i < EPT; i++) {
        int e = base + i * 256 + t;      // coalesced
        if (e < N_EDGES) {
            int d = dst[e], s = src[e];
            int b = d >> BSHIFT;
            int r = atomicAdd(&lhist[b], 1);   // in-block rank within bucket
            rec[i] = ((unsigned int)d << 16) | (unsigned int)s;
            br[i]  = (b << 16) | r;            // r < 4096 fits
        } else {
            br[i] = -1;
        }
    }
    __syncthreads();
    for (int i = t; i < NBUCK; i += 256) {
        int c = lhist[i];
        gbase[i] = c ? atomicAdd(&bcur[i * BPAD], c) : 0;
    }
    __syncthreads();
#pragma unroll
    for (int i = 0; i < EPT; i++) {
        if (br[i] >= 0) {
            int b = br[i] >> 16, r = br[i] & 0xffff;
            stag[gbase[b] + r] = rec[i];
        }
    }
}

// ---------------- per-bucket: LDS count + scan -> padded CSR rows ----------------
// Rows padded to multiples of 8 with DUMMY (zero hd row) -> branch-free agg.

__global__ void k_csr2(const unsigned int* __restrict__ stag, const int* __restrict__ bcur,
                       int* __restrict__ cnt, int* __restrict__ pcurg,
                       float* __restrict__ dinv, unsigned short* __restrict__ csr16) {
    __shared__ int lcnt[BSIZE], ltmp[BSIZE], lcur[BSIZE];
    int b = blockIdx.x, t = threadIdx.x;
    int bstart = b * SCAP;
    int bend   = bcur[b * BPAD];         // post-append cursor = bucket end
    lcnt[t] = 0;
    __syncthreads();
    for (int i = bstart + t; i < bend; i += 256)
        atomicAdd(&lcnt[(stag[i] >> 16) & (BSIZE - 1)], 1);
    __syncthreads();
    int v = lcnt[t];
    int p = (v + 7) & ~7;                // padded row size
    ltmp[t] = p;
    __syncthreads();
    for (int off = 1; off < 256; off <<= 1) {
        int u = (t >= off) ? ltmp[t - off] : 0;
        __syncthreads();
        ltmp[t] += u;
        __syncthreads();
    }
    int pstart = b * PBK + ltmp[t] - p;  // node's padded CSR row start
    lcur[t] = pstart;
    int node = (b << BSHIFT) + t;
    if (node < N_NODES) {
        cnt[node]   = v;
        pcurg[node] = pstart;
        dinv[node]  = rsqrtf((float)(v + 1));
    }
    __syncthreads();
    for (int i = bstart + t; i < bend; i += 256) {
        unsigned int rec = stag[i];
        int pos = atomicAdd(&lcur[(rec >> 16) & (BSIZE - 1)], 1);
        csr16[pos] = (unsigned short)rec;
    }
    for (int i = v; i < p; i++)          // fill pad slots with dummy zero-row
        csr16[pstart + i] = (unsigned short)DUMMY;
}

// ---------------- layer-0 GEMM (tiled, 4 acc/thread): hd = half((x@W0)*dinv) ----------------

__global__ __launch_bounds__(256) void k_gemm0(const float* __restrict__ A,
                                               const float* __restrict__ W,
                                               const float* __restrict__ dinv,
                                               __half* __restrict__ hd) {
    __shared__ float As[16][128];
    int tid = threadIdx.x;
    int j  = tid & 63;
    int nl = tid >> 6;              // 0..3
    int node0 = blockIdx.x * 16;

    const float4* srcp = (const float4*)(A + (size_t)node0 * 128);
    float4* dstp = (float4*)&As[0][0];
    for (int idx = tid; idx < 16 * 128 / 4; idx += 256) dstp[idx] = srcp[idx];
    __syncthreads();

    float acc[4] = {0.f, 0.f, 0.f, 0.f};
#pragma unroll
    for (int k = 0; k < 128; k += 4) {
        float4 a0 = *(const float4*)&As[nl * 4 + 0][k];   // wave-uniform broadcast
        float4 a1 = *(const float4*)&As[nl * 4 + 1][k];
        float4 a2 = *(const float4*)&As[nl * 4 + 2][k];
        float4 a3 = *(const float4*)&As[nl * 4 + 3][k];
        float w0 = W[(k + 0) * 64 + j];
        float w1 = W[(k + 1) * 64 + j];
        float w2 = W[(k + 2) * 64 + j];
        float w3 = W[(k + 3) * 64 + j];
        acc[0] = fmaf(a0.w, w3, fmaf(a0.z, w2, fmaf(a0.y, w1, fmaf(a0.x, w0, acc[0]))));
        acc[1] = fmaf(a1.w, w3, fmaf(a1.z, w2, fmaf(a1.y, w1, fmaf(a1.x, w0, acc[1]))));
        acc[2] = fmaf(a2.w, w3, fmaf(a2.z, w2, fmaf(a2.y, w1, fmaf(a2.x, w0, acc[2]))));
        acc[3] = fmaf(a3.w, w3, fmaf(a3.z, w2, fmaf(a3.y, w1, fmaf(a3.x, w0, acc[3]))));
    }
#pragma unroll
    for (int i = 0; i < 4; i++) {
        int n = node0 + nl * 4 + i;
        hd[(size_t)n * 64 + j] = __float2half(acc[i] * dinv[n]);
    }
}

// ---------------- agg for one node by one wave (branch-free, padded rows) ----------------

__device__ __forceinline__ float2 agg_node(const __half2* __restrict__ hd,
                                           const int* __restrict__ cnt,
                                           const int* __restrict__ pcur,
                                           const unsigned short* __restrict__ csr16,
                                           int n, int j, int hw) {
    int k = pcur[n];
    int iters = (cnt[n] + 7) >> 3;
    float sx = 0.f, sy = 0.f;
#pragma unroll 2
    for (int it = 0; it < iters; ++it, k += 8) {
        int s0 = csr16[k + hw],     s1 = csr16[k + 2 + hw];
        int s2 = csr16[k + 4 + hw], s3 = csr16[k + 6 + hw];
        float2 v0 = __half22float2(hd[(size_t)s0 * 32 + j]);
        float2 v1 = __half22float2(hd[(size_t)s1 * 32 + j]);
        float2 v2 = __half22float2(hd[(size_t)s2 * 32 + j]);
        float2 v3 = __half22float2(hd[(size_t)s3 * 32 + j]);
        sx += (v0.x + v1.x) + (v2.x + v3.x);
        sy += (v0.y + v1.y) + (v2.y + v3.y);
    }
    sx += __shfl_xor(sx, 32);
    sy += __shfl_xor(sy, 32);
    return make_float2(sx, sy);
}

// ---------------- fused: agg(layer l, wave=node) + gemm(layer l+1, wave0 4-acc) ----------------

__global__ __launch_bounds__(256) void k_fused(const __half2* __restrict__ hd_in,
                                               const float* __restrict__ b,
                                               const float* __restrict__ dinv,
                                               const int* __restrict__ cnt,
                                               const int* __restrict__ pcur,
                                               const unsigned short* __restrict__ csr16,
                                               const float* __restrict__ W,
                                               __half* __restrict__ hs_out,
                                               __half* __restrict__ hd_out) {
    __shared__ float As[4][64];
    int tid = threadIdx.x;
    int w = tid >> 6, lane = tid & 63;
    int j = lane & 31, hw = lane >> 5;
    int node0 = blockIdx.x * 4;
    int n = node0 + w;

    float2 s = agg_node(hd_in, cnt, pcur, csr16, n, j, hw);
    if (hw == 0) {
        float dv = dinv[n];
        float2 sv = __half22float2(hd_in[(size_t)n * 32 + j]);   // self row
        float ox = fmaxf(fmaf(s.x + sv.x, dv, b[2 * j]), 0.f);
        float oy = fmaxf(fmaf(s.y + sv.y, dv, b[2 * j + 1]), 0.f);
        ((float2*)&As[w][0])[j] = make_float2(ox, oy);
        ((__half2*)hs_out)[(size_t)n * 32 + j] =
            __halves2half2(__float2half(ox), __float2half(oy));
    }
    __syncthreads();

    // wave 0: gemm for the block's 4 nodes, 4 acc/thread (4x W reuse, ILP 4)
    if (tid < 64) {
        float acc[4] = {0.f, 0.f, 0.f, 0.f};
#pragma unroll
        for (int k = 0; k < 64; k += 4) {
            float4 a0 = *(const float4*)&As[0][k];   // wave-uniform broadcasts
            float4 a1 = *(const float4*)&As[1][k];
            float4 a2 = *(const float4*)&As[2][k];
            float4 a3 = *(const float4*)&As[3][k];
            float w0 = W[(k + 0) * 64 + tid];
            float w1 = W[(k + 1) * 64 + tid];
            float w2 = W[(k + 2) * 64 + tid];
            float w3 = W[(k + 3) * 64 + tid];
            acc[0] = fmaf(a0.w, w3, fmaf(a0.z, w2, fmaf(a0.y, w1, fmaf(a0.x, w0, acc[0]))));
            acc[1] = fmaf(a1.w, w3, fmaf(a1.z, w2, fmaf(a1.y, w1, fmaf(a1.x, w0, acc[1]))));
            acc[2] = fmaf(a2.w, w3, fmaf(a2.z, w2, fmaf(a2.y, w1, fmaf(a2.x, w0, acc[2]))));
            acc[3] = fmaf(a3.w, w3, fmaf(a3.z, w2, fmaf(a3.y, w1, fmaf(a3.x, w0, acc[3]))));
        }
#pragma unroll
        for (int i = 0; i < 4; i++) {
            int nn = node0 + i;
            hd_out[(size_t)nn * 64 + tid] = __float2half(acc[i] * dinv[nn]);
        }
    }
}

// ---------------- last: agg(l3) + attention + projection(wave0 4-acc) ----------------

__global__ __launch_bounds__(256) void k_last(const __half2* __restrict__ hd_in,
                                              const float* __restrict__ b,
                                              const float* __restrict__ dinv,
                                              const int* __restrict__ cnt,
                                              const int* __restrict__ pcur,
                                              const unsigned short* __restrict__ csr16,
                                              const __half* __restrict__ hs16,
                                              const float* __restrict__ Wout,
                                              const float* __restrict__ bout,
                                              float* __restrict__ out) {
    __shared__ float As[4][64];
    int tid = threadIdx.x;
    int w = tid >> 6, lane = tid & 63;
    int j = lane & 31, hw = lane >> 5;
    int node0 = blockIdx.x * 4;
    int n = node0 + w;

    float2 s = agg_node(hd_in, cnt, pcur, csr16, n, j, hw);
    if (hw == 0) {
        float dv = dinv[n];
        float2 sv = __half22float2(hd_in[(size_t)n * 32 + j]);
        float ox = fmaxf(fmaf(s.x + sv.x, dv, b[2 * j]), 0.f);
        float oy = fmaxf(fmaf(s.y + sv.y, dv, b[2 * j + 1]), 0.f);
        ((float2*)&As[w][0])[j] = make_float2(ox, oy);
    }
    __builtin_amdgcn_wave_barrier();

    // attention over layers (wave = node; feature = lane)
    float v[N_LAYER], sc[N_LAYER];
#pragma unroll
    for (int l = 0; l < 3; l++) {
        float val = __half2float(hs16[((size_t)l * N_NODES + n) * 64 + lane]);
        v[l]  = val;
        sc[l] = val * val;
    }
    v[3]  = As[w][lane];
    sc[3] = v[3] * v[3];
#pragma unroll
    for (int off = 32; off > 0; off >>= 1) {
#pragma unroll
        for (int l = 0; l < N_LAYER; l++) sc[l] += __shfl_xor(sc[l], off, 64);
    }
    float m = fmaxf(fmaxf(sc[0], sc[1]), fmaxf(sc[2], sc[3]));
    float e[N_LAYER];
    float sum = 0.f;
#pragma unroll
    for (int l = 0; l < N_LAYER; l++) { e[l] = __expf(sc[l] - m); sum += e[l]; }
    float inv = 1.f / sum;
    float bl = 0.f;
#pragma unroll
    for (int l = 0; l < N_LAYER; l++) bl = fmaf(e[l] * inv, v[l], bl);
    As[w][lane] = bl;                     // own-thread address: ordered after read
    __syncthreads();

    // wave 0: projection for the block's 4 nodes, 4 acc/thread
    if (tid < 64 && tid < N_CLASS) {
        float acc[4] = {bout[tid], bout[tid], bout[tid], bout[tid]};
#pragma unroll
        for (int k = 0; k < 64; k += 4) {
            float4 a0 = *(const float4*)&As[0][k];
            float4 a1 = *(const float4*)&As[1][k];
            float4 a2 = *(const float4*)&As[2][k];
            float4 a3 = *(const float4*)&As[3][k];
            float w0 = Wout[(k + 0) * N_CLASS + tid];
            float w1 = Wout[(k + 1) * N_CLASS + tid];
            float w2 = Wout[(k + 2) * N_CLASS + tid];
            float w3 = Wout[(k + 3) * N_CLASS + tid];
            acc[0] = fmaf(a0.w, w3, fmaf(a0.z, w2, fmaf(a0.y, w1, fmaf(a0.x, w0, acc[0]))));
            acc[1] = fmaf(a1.w, w3, fmaf(a1.z, w2, fmaf(a1.y, w1, fmaf(a1.x, w0, acc[1]))));
            acc[2] = fmaf(a2.w, w3, fmaf(a2.z, w2, fmaf(a2.y, w1, fmaf(a2.x, w0, acc[2]))));
            acc[3] = fmaf(a3.w, w3, fmaf(a3.z, w2, fmaf(a3.y, w1, fmaf(a3.x, w0, acc[3]))));
        }
#pragma unroll
        for (int i = 0; i < 4; i++)
            out[(size_t)(node0 + i) * N_CLASS + tid] = acc[i];
    }
}

// ---------------- launch ----------------

extern "C" void kernel_launch(void* const* d_in, const int* in_sizes, int n_in,
                              void* d_out, int out_size, void* d_ws, size_t ws_size,
                              hipStream_t stream) {
    const float* x    = (const float*)d_in[0];
    const float* W0   = (const float*)d_in[1];
    const float* b0   = (const float*)d_in[2];
    const float* Ws   = (const float*)d_in[3];
    const float* bs   = (const float*)d_in[4];
    const float* Wout = (const float*)d_in[5];
    const float* bout = (const float*)d_in[6];
    const int*   ei   = (const int*)d_in[7];
    const int* src = ei;
    const int* dst = ei + N_EDGES;
    float* out = (float*)d_out;

    int*            cnt   = (int*)d_ws;                             // N
    int*            pcur  = cnt + N_NODES;                          // N
    int*            bcur  = pcur + N_NODES;                         // NBUCK*BPAD
    float*          dinv  = (float*)(bcur + NBUCK * BPAD);          // N
    unsigned short* csr16 = (unsigned short*)(dinv + N_NODES);      // NBUCK*PBK
    __half*         hdA   = (__half*)(csr16 + (size_t)NBUCK * PBK); // (N+1)*64
    __half*         hdB   = hdA + (size_t)(N_NODES + 1) * 64;       // (N+1)*64
    __half*         hs16  = hdB + (size_t)(N_NODES + 1) * 64;       // 3*N*64
    unsigned int*   stag  = (unsigned int*)hs16;                    // NBUCK*SCAP, aliased (build only)

    k_zerob <<<1, 256, 0, stream>>>(bcur, hdA, hdB);
    k_bucket<<<NBBLK, 256, 0, stream>>>(src, dst, bcur, stag);
    k_csr2  <<<NBUCK, 256, 0, stream>>>(stag, bcur, cnt, pcur, dinv, csr16);

    k_gemm0<<<N_NODES / 16, 256, 0, stream>>>(x, W0, dinv, hdA);

    const int NB = N_NODES / 4;   // 12500 blocks x 256 threads, wave = node (agg)

    k_fused<<<NB, 256, 0, stream>>>((const __half2*)hdA, b0, dinv, cnt, pcur, csr16,
                                    Ws + 0 * 64 * 64, hs16 + (size_t)0 * N_NODES * 64, hdB);
    k_fused<<<NB, 256, 0, stream>>>((const __half2*)hdB, bs + 0 * 64, dinv, cnt, pcur, csr16,
                                    Ws + 1 * 64 * 64, hs16 + (size_t)1 * N_NODES * 64, hdA);
    k_fused<<<NB, 256, 0, stream>>>((const __half2*)hdA, bs + 1 * 64, dinv, cnt, pcur, csr16,
                                    Ws + 2 * 64 * 64, hs16 + (size_t)2 * N_NODES * 64, hdB);
    k_last <<<NB, 256, 0, stream>>>((const __half2*)hdB, bs + 2 * 64, dinv, cnt, pcur, csr16,
                                    hs16, Wout, bout, out);
}